// Round 9
// baseline (3781.024 us; speedup 1.0000x reference)
//
#include <hip/hip_runtime.h>
#include <cstddef>

typedef unsigned short u16;
typedef __bf16 bf16x8 __attribute__((ext_vector_type(8)));
typedef float f32x4 __attribute__((ext_vector_type(4)));
typedef unsigned short us4 __attribute__((ext_vector_type(4)));

__device__ __forceinline__ u16 f2b(float f) {
    unsigned u = __float_as_uint(f);
    u += 0x7fffu + ((u >> 16) & 1u);          // round-to-nearest-even
    return (u16)(u >> 16);
}
__device__ __forceinline__ float b2f(u16 h) { return __uint_as_float(((unsigned)h) << 16); }

__device__ __forceinline__ f32x4 mfma16(bf16x8 a, bf16x8 b, f32x4 c) {
    return __builtin_amdgcn_mfma_f32_16x16x32_bf16(a, b, c, 0, 0, 0);
}

// pin a 128-bit value into the AGPR file (gfx950 unified RF: MFMA reads B
// straight from AGPR; builtin keeps compiler hazard handling).
__device__ __forceinline__ void pin_agpr(bf16x8& v) { asm volatile("" : "+a"(v)); }

// barrier WITHOUT vmcnt drain: global stores/prefetch loads stay in flight.
__device__ __forceinline__ void bar_lds() {
    asm volatile("s_waitcnt lgkmcnt(0)\n\ts_barrier" ::: "memory");
}

// B=256, S=512, D=128, H=256, HH=128, L=64.  chunk = 32 steps, 16 chunks.
#define CH   32
#define NCH  16
#define MCH  (CH * 256)   // rows per chunk = 8192

// ---------------------------------------------------------------------------
// pack: W [N][K] f32 -> MFMA B-fragments bf16; frag f=(nt*KT+kt): 64 lanes x 8
//   B[k][n] = W[n][k],  n = nt*16 + (lane&15),  k = kt*32 + (lane>>4)*8 + j
// ---------------------------------------------------------------------------
struct PackSeg { const float* src; u16* dst; int K; int nfrag; };
struct PackArgs { PackSeg seg[8]; };

__global__ __launch_bounds__(64) void pack_all(PackArgs pa) {
    int f = blockIdx.x;
    int i = 0;
    while (i < 7 && f >= pa.seg[i].nfrag) { f -= pa.seg[i].nfrag; i++; }
    const float* W = pa.seg[i].src;
    u16* out = pa.seg[i].dst;
    int K = pa.seg[i].K;
    int lane = threadIdx.x, q = lane >> 4, ln = lane & 15;
    int KT = K >> 5;
    int nt = f / KT, kt = f % KT;
    int n = nt * 16 + ln;
    int kb = kt * 32 + q * 8;
#pragma unroll
    for (int j = 0; j < 8; j++)
        out[((size_t)f * 64 + lane) * 8 + j] = f2b(W[(size_t)n * K + kb + j]);
}

// ---------------------------------------------------------------------------
__global__ void zero_kernel(float* __restrict__ st, float* __restrict__ lossslot) {
    int i = blockIdx.x * 256 + threadIdx.x;
    if (i < 196608) st[i] = 0.f;
    if (i == 0) *lossslot = 0.f;
}

// emb[row=t*256+b][d] = path[tok0][d] + sys[tok1][d]   (bf16). 16 rows/block.
__global__ __launch_bounds__(256) void embed_kernel(const int* __restrict__ tok,
                                                    const float* __restrict__ pw,
                                                    const float* __restrict__ sw,
                                                    u16* __restrict__ emb) {
    int col = threadIdx.x & 127;
    int half = threadIdx.x >> 7;
    int rbase = blockIdx.x * 16;
#pragma unroll
    for (int i = 0; i < 8; i++) {
        int r = rbase + i * 2 + half;   // row = t*256 + b
        int b = r & 255, t = r >> 8;
        const int* tp = tok + ((size_t)b * 512 + t) * 2;
        float v = pw[(size_t)tp[0] * 128 + col] + sw[(size_t)tp[1] * 128 + col];
        emb[(size_t)r * 128 + col] = f2b(v);
    }
}

// ---------------------------------------------------------------------------
// gemm body (512 thr): gi[M=8192][N] = X @ W.T + bias (+bhh for r,z gates),
// written TRANSPOSED: giT[(t*16+bg)*N + g][16] with bl=batch%16 innermost,
// so rec's per-step C-init is contiguous b64 loads.
// ---------------------------------------------------------------------------
template <int K, int N>
__device__ __forceinline__ void gemm_body(int bid, char* ldsraw,
                                          const u16* __restrict__ X,
                                          const u16* __restrict__ Wp,
                                          const float* __restrict__ bias,
                                          const float* __restrict__ bhh,
                                          u16* __restrict__ out) {
    constexpr int NH = N / 2, KT = K / 32, NTL = NH / 16;
    u16* wl = (u16*)ldsraw;
    int tid = threadIdx.x, wid = tid >> 6, lane = tid & 63, q = lane >> 4, ln = lane & 15;
    int half = bid & 1, mg = bid >> 1;
    {
        const bf16x8* src = (const bf16x8*)(Wp + (size_t)half * NH * K);
        bf16x8* dst = (bf16x8*)wl;
#pragma unroll
        for (int i = 0; i < NH * K / 8 / 512; i++) dst[tid + i * 512] = src[tid + i * 512];
    }
    __syncthreads();
    int m0 = (mg * 8 + wid) * 16;
    int t = m0 >> 8, bg = (m0 >> 4) & 15;
    u16* obase = out + (size_t)(t * 16 + bg) * N * 16;
    bf16x8 af[KT];
#pragma unroll
    for (int kt = 0; kt < KT; kt++)
        af[kt] = *(const bf16x8*)(X + (size_t)(m0 + ln) * K + kt * 32 + q * 8);
    for (int nt = 0; nt < NTL; nt++) {
        f32x4 acc = {0.f, 0.f, 0.f, 0.f};
#pragma unroll
        for (int kt = 0; kt < KT; kt++)
            acc = mfma16(af[kt], *(const bf16x8*)&wl[((nt * KT + kt) * 64 + lane) * 8], acc);
        int g = half * NH + nt * 16 + ln;
        float bv = bias[g] + ((g < 2 * (N / 3)) ? bhh[g] : 0.f);
        us4 v;
#pragma unroll
        for (int r = 0; r < 4; r++) v[r] = f2b(acc[r] + bv);
        *(us4*)&obase[(size_t)g * 16 + 4 * q] = v;
    }
}

template <int K, int N>
__global__ __launch_bounds__(512, 2) void gemm_kernel(const u16* __restrict__ X,
                                                      const u16* __restrict__ Wp,
                                                      const float* __restrict__ bias,
                                                      const float* __restrict__ bhh,
                                                      u16* __restrict__ out) {
    __shared__ char lds[98304];
    gemm_body<K, N>(blockIdx.x, lds, X, Wp, bias, bhh, out);
}

// ---------------------------------------------------------------------------
// loss body (512 thr, 64 blocks): recon = h2 @ l2W.T + l2b ; MSE vs emb chunk
// ---------------------------------------------------------------------------
__device__ __forceinline__ void loss_body(int bid, char* ldsraw,
                                          const u16* __restrict__ h2d,
                                          const u16* __restrict__ Wp,
                                          const float* __restrict__ l2b,
                                          const u16* __restrict__ embc,
                                          float* __restrict__ loss) {
    float* red = (float*)ldsraw;
    int tid = threadIdx.x, wid = tid >> 6, lane = tid & 63, q = lane >> 4, ln = lane & 15;
    int m0 = (bid * 8 + wid) * 16;
    bf16x8 af[8];
#pragma unroll
    for (int kt = 0; kt < 8; kt++)
        af[kt] = *(const bf16x8*)(h2d + (size_t)(m0 + ln) * 256 + kt * 32 + q * 8);
    float ls = 0.f;
#pragma unroll
    for (int nt = 0; nt < 8; nt++) {
        f32x4 acc = {0.f, 0.f, 0.f, 0.f};
#pragma unroll
        for (int kt = 0; kt < 8; kt++)
            acc = mfma16(af[kt], *(const bf16x8*)(Wp + ((size_t)(nt * 8 + kt) * 64 + lane) * 8), acc);
        int g = nt * 16 + ln;
        float bv = l2b[g];
#pragma unroll
        for (int r = 0; r < 4; r++) {
            float rec = acc[r] + bv;
            float ev = b2f(embc[(size_t)(m0 + q * 4 + r) * 128 + g]);
            float d = rec - ev;
            ls += d * d;
        }
    }
    red[tid] = ls;
    __syncthreads();
    for (int s = 256; s > 0; s >>= 1) {
        if (tid < s) red[tid] += red[tid + s];
        __syncthreads();
    }
    if (tid == 0) atomicAdd(loss, red[0] * (1.f / 16777216.f));
}

// ---------------------------------------------------------------------------
// Recurrent GRU body. R8 structure, one change: ALL weight tiles pinned into
// AGPRs via "+a" asm (gfx950 unified RF: 192 AGPR + ~120 VGPR < 512/wave cap
// at 2 waves/SIMD). Removes the per-step LDS weight-tile reads entirely
// (64 b128/CU/step) -- rec LDS is now just the h double-buffer. kh-outer
// 6-chain interleave; bhn folded into n-gate C-init; ONE light barrier/step;
// gi prefetched one step ahead from the transposed layout.
// ---------------------------------------------------------------------------
template <int H, bool GI_CONST, bool WRITE_SEQ>
__device__ __forceinline__ void rec_body(int bid, char* ldsraw,
                                         const u16* __restrict__ giT,
                                         const float* __restrict__ gic,
                                         const u16* __restrict__ Wp,
                                         const float* __restrict__ bhh,
                                         float* __restrict__ hstate,
                                         u16* __restrict__ hseq, int steps) {
    constexpr int G3 = 3 * H;
    constexpr int KT = H / 32;
    constexpr int NHF = H / 128;            // h-slices per wave: 2 (H=256) / 1 (H=128)
    constexpr int HP = H + 8;
    u16 (*hl)[16][HP] = (u16 (*)[16][HP])ldsraw;

    const int tid = threadIdx.x, w = tid >> 6, lane = tid & 63, q = lane >> 4, ln = lane & 15;
    const int b0 = bid * 16;
    const bf16x8* wpv = (const bf16x8*)Wp;

    // ---- ALL weight tiles AGPR-resident (pinned) ----
    bf16x8 wfr[3][NHF][KT];
#pragma unroll
    for (int g = 0; g < 3; g++)
#pragma unroll
        for (int hh = 0; hh < NHF; hh++)
#pragma unroll
            for (int kt = 0; kt < KT; kt++) {
                wfr[g][hh][kt] = wpv[((size_t)(g * (H / 16) + NHF * w + hh) * KT + kt) * 64 + lane];
                pin_agpr(wfr[g][hh][kt]);
            }
    float bhn_r[NHF];
#pragma unroll
    for (int hh = 0; hh < NHF; hh++) bhn_r[hh] = bhh[2 * H + 16 * (NHF * w + hh) + ln];

    // ---- init h (bf16-rounded, matches chunk carry) ----
    float hold[NHF][4];
#pragma unroll
    for (int hh = 0; hh < NHF; hh++)
#pragma unroll
        for (int rg = 0; rg < 4; rg++) {
            const int b = 4 * q + rg, k = 16 * (NHF * w + hh) + ln;
            u16 hb = f2b(hstate[(size_t)(b0 + b) * H + k]);
            hold[hh][rg] = b2f(hb);
            hl[0][b][k] = hb;
        }

    // ---- gi: constant (f32) or transposed-chunk prefetch (us4/lane/tile) ----
    float gcf[3][NHF][4];
    us4 gp[3][NHF];
    if (GI_CONST) {
#pragma unroll
        for (int g = 0; g < 3; g++)
#pragma unroll
            for (int hh = 0; hh < NHF; hh++)
#pragma unroll
                for (int rg = 0; rg < 4; rg++)
                    gcf[g][hh][rg] =
                        gic[(size_t)(b0 + 4 * q + rg) * G3 + g * H + 16 * (NHF * w + hh) + ln];
    } else {
        const u16* blk = giT + (size_t)bid * G3 * 16;
#pragma unroll
        for (int g = 0; g < 3; g++)
#pragma unroll
            for (int hh = 0; hh < NHF; hh++)
                gp[g][hh] = *(const us4*)&blk[(g * H + 16 * (NHF * w + hh) + ln) * 16 + 4 * q];
    }
    bar_lds();

    for (int t = 0; t < steps; t++) {
        const int p = t & 1;
        // ---- C-init: r,z from gi; n-gate from bhn (folded); n-gi kept aside ----
        float gf2[NHF][4];
        f32x4 acc[3][NHF];
#pragma unroll
        for (int hh = 0; hh < NHF; hh++) {
#pragma unroll
            for (int rg = 0; rg < 4; rg++) {
                if (GI_CONST) {
                    acc[0][hh][rg] = gcf[0][hh][rg];
                    acc[1][hh][rg] = gcf[1][hh][rg];
                    gf2[hh][rg] = gcf[2][hh][rg];
                } else {
                    acc[0][hh][rg] = b2f(gp[0][hh][rg]);
                    acc[1][hh][rg] = b2f(gp[1][hh][rg]);
                    gf2[hh][rg] = b2f(gp[2][hh][rg]);
                }
                acc[2][hh][rg] = bhn_r[hh];
            }
        }
        // prefetch next step's gi (single-buffered; consumed above)
        if (!GI_CONST) {
            const int tn = (t + 1 < steps) ? t + 1 : t;
            const u16* blk = giT + (size_t)(tn * 16 + bid) * G3 * 16;
#pragma unroll
            for (int g = 0; g < 3; g++)
#pragma unroll
                for (int hh = 0; hh < NHF; hh++)
                    gp[g][hh] = *(const us4*)&blk[(g * H + 16 * (NHF * w + hh) + ln) * 16 + 4 * q];
        }

        // ---- gh = h @ Whh.T : kh-outer, 6 chains interleaved (max ILP) ----
#pragma unroll
        for (int kh = 0; kh < KT / 2; kh++) {
            bf16x8 a0 = *(const bf16x8*)&hl[p][ln][(2 * kh) * 32 + q * 8];
            bf16x8 a1 = *(const bf16x8*)&hl[p][ln][(2 * kh + 1) * 32 + q * 8];
#pragma unroll
            for (int g = 0; g < 3; g++)
#pragma unroll
                for (int hh = 0; hh < NHF; hh++) {
                    acc[g][hh] = mfma16(a0, wfr[g][hh][2 * kh], acc[g][hh]);
                    acc[g][hh] = mfma16(a1, wfr[g][hh][2 * kh + 1], acc[g][hh]);
                }
        }

        u16* hsb = WRITE_SEQ ? (hseq + ((size_t)t * 256 + b0) * H) : nullptr;
        // ---- in-register recombine ----
#pragma unroll
        for (int hh = 0; hh < NHF; hh++) {
            const int k = 16 * (NHF * w + hh) + ln;
#pragma unroll
            for (int rg = 0; rg < 4; rg++) {
                float xr = acc[0][hh][rg];
                float xz = acc[1][hh][rg];
                float hn = acc[2][hh][rg];          // bhn already in C-init
                float r = __builtin_amdgcn_rcpf(1.f + __builtin_amdgcn_exp2f(-1.44269504f * xr));
                float z = __builtin_amdgcn_rcpf(1.f + __builtin_amdgcn_exp2f(-1.44269504f * xz));
                float y = gf2[hh][rg] + r * hn;
                float e2 = __builtin_amdgcn_exp2f(2.88539008f * y);
                float n = 1.f - 2.f * __builtin_amdgcn_rcpf(e2 + 1.f);
                float hv = n + z * (hold[hh][rg] - n);
                u16 hb = f2b(hv);
                hold[hh][rg] = b2f(hb);
                hl[p ^ 1][4 * q + rg][k] = hb;
                if (WRITE_SEQ) hsb[(size_t)(4 * q + rg) * H + k] = hb;
            }
        }
        bar_lds();
    }
#pragma unroll
    for (int hh = 0; hh < NHF; hh++)
#pragma unroll
        for (int rg = 0; rg < 4; rg++)
            hstate[(size_t)(b0 + 4 * q + rg) * H + 16 * (NHF * w + hh) + ln] = hold[hh][rg];
}

// ---------------------------------------------------------------------------
// pair dispatches: independent WGs. rec WGs lowest blockIdx grab CUs first;
// 98 KB LDS pins 1 WG/CU everywhere (gemm WGs never share a rec CU).
// ---------------------------------------------------------------------------
__global__ __launch_bounds__(512, 2) void enc_pair(
    int nb1, int nb2, int ng1,
    const u16* r1gi, const u16* r1W, const float* r1bhh, float* r1st, u16* r1seq,
    const u16* r2gi, const u16* r2W, const float* r2bhh, float* r2st,
    const u16* g1X, const u16* g1W, const float* g1b, const float* g1bhh, u16* g1out,
    const u16* g2X, const u16* g2W, const float* g2b, const float* g2bhh, u16* g2out,
    int steps) {
    __shared__ char lds[98304];
    int b = blockIdx.x;
    if (b < nb1)
        rec_body<256, false, true>(b, lds, r1gi, nullptr, r1W, r1bhh, r1st, r1seq, steps);
    else if (b < nb1 + nb2)
        rec_body<128, false, false>(b - nb1, lds, r2gi, nullptr, r2W, r2bhh, r2st, nullptr, steps);
    else if (b < nb1 + nb2 + ng1)
        gemm_body<128, 768>(b - nb1 - nb2, lds, g1X, g1W, g1b, g1bhh, g1out);
    else
        gemm_body<256, 384>(b - nb1 - nb2 - ng1, lds, g2X, g2W, g2b, g2bhh, g2out);
}

__global__ __launch_bounds__(512, 2) void dec_pair(
    int nb1, int nb2, int ng,
    const float* r1gic, const u16* r1W, const float* r1bhh, float* r1st, u16* r1seq,
    const u16* r2gi, const u16* r2W, const float* r2bhh, float* r2st, u16* r2seq,
    const u16* gX, const u16* gW, const float* gb, const float* gbhh, u16* gout,
    const u16* lh2, const u16* lW, const float* l2b, const u16* lemb, float* lloss,
    int steps) {
    __shared__ char lds[98304];
    int b = blockIdx.x;
    if (b < nb1)
        rec_body<128, true, true>(b, lds, nullptr, r1gic, r1W, r1bhh, r1st, r1seq, steps);
    else if (b < nb1 + nb2)
        rec_body<256, false, true>(b - nb1, lds, r2gi, nullptr, r2W, r2bhh, r2st, r2seq, steps);
    else if (b < nb1 + nb2 + ng)
        gemm_body<128, 768>(b - nb1 - nb2, lds, gX, gW, gb, gbhh, gout);
    else
        loss_body(b - nb1 - nb2 - ng, lds, lh2, lW, l2b, lemb, lloss);
}

// ---------------------------------------------------------------------------
// latent = st2 @ l1_W.T + l1_b (-> d_out) ; gi1dec = latent @ d1_Wih.T + d1bih
// (+ d1bhh folded for r,z gates)
// ---------------------------------------------------------------------------
__global__ __launch_bounds__(128) void latent_kernel(const float* __restrict__ st2,
                                                     const float* __restrict__ l1W,
                                                     const float* __restrict__ l1b,
                                                     const float* __restrict__ d1Wih,
                                                     const float* __restrict__ d1bih,
                                                     const float* __restrict__ d1bhh,
                                                     float* __restrict__ dout,
                                                     float* __restrict__ gi1dec) {
    __shared__ float hv[128], lat[64];
    int b = blockIdx.x, tid = threadIdx.x;
    hv[tid] = st2[(size_t)b * 128 + tid];
    __syncthreads();
    if (tid < 64) {
        float s = l1b[tid];
        for (int k = 0; k < 128; k++) s += l1W[tid * 128 + k] * hv[k];
        dout[b * 64 + tid] = s;
        lat[tid] = s;
    }
    __syncthreads();
    for (int g = tid; g < 384; g += 128) {
        float s = d1bih[g] + (g < 256 ? d1bhh[g] : 0.f);
        for (int k = 0; k < 64; k++) s += d1Wih[g * 64 + k] * lat[k];
        gi1dec[(size_t)b * 384 + g] = s;
    }
}

// ---------------------------------------------------------------------------
extern "C" void kernel_launch(void* const* d_in, const int* in_sizes, int n_in,
                              void* d_out, int out_size, void* d_ws, size_t ws_size,
                              hipStream_t stream) {
    (void)in_sizes; (void)n_in; (void)out_size; (void)ws_size;
    const int*   tok   = (const int*)d_in[0];
    const float* pw    = (const float*)d_in[1];
    const float* sw    = (const float*)d_in[2];
    const float* e1Wih = (const float*)d_in[3];
    const float* e1Whh = (const float*)d_in[4];
    const float* e1bih = (const float*)d_in[5];
    const float* e1bhh = (const float*)d_in[6];
    const float* e2Wih = (const float*)d_in[7];
    const float* e2Whh = (const float*)d_in[8];
    const float* e2bih = (const float*)d_in[9];
    const float* e2bhh = (const float*)d_in[10];
    const float* l1W   = (const float*)d_in[11];
    const float* l1b   = (const float*)d_in[12];
    const float* d1Wih = (const float*)d_in[13];
    const float* d1Whh = (const float*)d_in[14];
    const float* d1bih = (const float*)d_in[15];
    const float* d1bhh = (const float*)d_in[16];
    const float* d2Wih = (const float*)d_in[17];
    const float* d2Whh = (const float*)d_in[18];
    const float* d2bih = (const float*)d_in[19];
    const float* d2bhh = (const float*)d_in[20];
    const float* l2W   = (const float*)d_in[21];
    const float* l2b   = (const float*)d_in[22];
    float* dout = (float*)d_out;

    char* base = (char*)d_ws;
    size_t o = 0;
    auto alloc = [&](size_t bytes) { size_t r = o; o += (bytes + 255) & ~(size_t)255; return r; };
    u16* e1Wih_p = (u16*)(base + alloc(196608));
    u16* e1Whh_p = (u16*)(base + alloc(393216));
    u16* e2Wih_p = (u16*)(base + alloc(196608));
    u16* e2Whh_p = (u16*)(base + alloc(98304));
    u16* d1Whh_p = (u16*)(base + alloc(98304));
    u16* d2Wih_p = (u16*)(base + alloc(196608));
    u16* d2Whh_p = (u16*)(base + alloc(393216));
    u16* l2W_p   = (u16*)(base + alloc(65536));
    u16* emb_p   = (u16*)(base + alloc((size_t)131072 * 128 * 2));
    u16* giA0    = (u16*)(base + alloc((size_t)MCH * 768 * 2));   // transposed
    u16* giA1    = (u16*)(base + alloc((size_t)MCH * 768 * 2));
    u16* giB0    = (u16*)(base + alloc((size_t)MCH * 384 * 2));   // transposed
    u16* giB1    = (u16*)(base + alloc((size_t)MCH * 384 * 2));
    u16* h1c0    = (u16*)(base + alloc((size_t)MCH * 256 * 2));   // row layout
    u16* h1c1    = (u16*)(base + alloc((size_t)MCH * 256 * 2));
    u16* h2c0    = (u16*)(base + alloc((size_t)MCH * 256 * 2));
    u16* h2c1    = (u16*)(base + alloc((size_t)MCH * 256 * 2));
    float* st1 = (float*)(base + alloc(256 * 256 * 4));
    float* st2 = (float*)(base + alloc(256 * 128 * 4));
    float* st3 = (float*)(base + alloc(256 * 128 * 4));
    float* st4 = (float*)(base + alloc(256 * 256 * 4));
    float* gi1dec = (float*)(base + alloc(256 * 384 * 4));
    u16* giA[2] = {giA0, giA1};
    u16* giB[2] = {giB0, giB1};
    u16* h1c[2] = {h1c0, h1c1};
    u16* h2c[2] = {h2c0, h2c1};

    PackArgs pa;
    pa.seg[0] = {e1Wih, e1Wih_p, 128, 192};
    pa.seg[1] = {e1Whh, e1Whh_p, 256, 384};
    pa.seg[2] = {e2Wih, e2Wih_p, 256, 192};
    pa.seg[3] = {e2Whh, e2Whh_p, 128, 96};
    pa.seg[4] = {d1Whh, d1Whh_p, 128, 96};
    pa.seg[5] = {d2Wih, d2Wih_p, 128, 192};
    pa.seg[6] = {d2Whh, d2Whh_p, 256, 384};
    pa.seg[7] = {l2W,   l2W_p,   256, 64};
    pack_all<<<1600, 64, 0, stream>>>(pa);
    zero_kernel<<<769, 256, 0, stream>>>(st1, dout + 16384);  // st1..st4 contiguous
    embed_kernel<<<8192, 256, 0, stream>>>(tok, pw, sw, emb_p);

    // ---------------- encoder: e1rec(c) || e2rec(c-2) || e1gemm(c+1) || e2gemm(c-1)
    gemm_kernel<128, 768><<<128, 512, 0, stream>>>(emb_p, e1Wih_p, e1bih, e1bhh, giA[0]);
    for (int c = 0; c < NCH; c++) {
        int nb2 = (c >= 2) ? 16 : 0;
        int ng1 = (c <= NCH - 2) ? 128 : 0;
        int ng2 = (c >= 1) ? 128 : 0;
        enc_pair<<<16 + nb2 + ng1 + ng2, 512, 0, stream>>>(16, nb2, ng1,
            giA[c & 1], e1Whh_p, e1bhh, st1, h1c[c & 1],
            giB[(c - 2) & 1], e2Whh_p, e2bhh, st2,
            emb_p + (size_t)((c + 1) & (NCH - 1)) * MCH * 128, e1Wih_p, e1bih, e1bhh,
            giA[(c + 1) & 1],
            h1c[(c - 1) & 1], e2Wih_p, e2bih, e2bhh, giB[(c - 1) & 1], CH);
    }
    // tails: e2rec(NCH-2) || e2gemm(NCH-1);  e2rec(NCH-1)
    enc_pair<<<16 + 128, 512, 0, stream>>>(0, 16, 0,
        giA[0], e1Whh_p, e1bhh, st1, h1c[0],
        giB[(NCH - 2) & 1], e2Whh_p, e2bhh, st2,
        emb_p, e1Wih_p, e1bih, e1bhh, giA[0],
        h1c[(NCH - 1) & 1], e2Wih_p, e2bih, e2bhh, giB[(NCH - 1) & 1], CH);
    enc_pair<<<16, 512, 0, stream>>>(0, 16, 0,
        giA[0], e1Whh_p, e1bhh, st1, h1c[0],
        giB[(NCH - 1) & 1], e2Whh_p, e2bhh, st2,
        emb_p, e1Wih_p, e1bih, e1bhh, giA[0],
        h1c[0], e2Wih_p, e2bih, e2bhh, giB[0], CH);

    latent_kernel<<<256, 128, 0, stream>>>(st2, l1W, l1b, d1Wih, d1bih, d1bhh, dout, gi1dec);

    // ---------------- decoder: d1rec(c) || d2gemm(c-1) || d2rec(c-2) || loss(c-3)
    for (int c = 0; c <= NCH + 2; c++) {
        int nb1 = (c <= NCH - 1) ? 16 : 0;
        int ng  = (c >= 1 && c <= NCH) ? 128 : 0;
        int nb2 = (c >= 2 && c <= NCH + 1) ? 16 : 0;
        int nl  = (c >= 3) ? 64 : 0;
        dec_pair<<<nb1 + nb2 + ng + nl, 512, 0, stream>>>(nb1, nb2, ng,
            gi1dec, d1Whh_p, d1bhh, st3, h1c[c & 1],
            giA[(c - 2) & 1], d2Whh_p, d2bhh, st4, h2c[(c - 2) & 1],
            h1c[(c - 1) & 1], d2Wih_p, d2bih, d2bhh, giA[(c - 1) & 1],
            h2c[(c - 3) & 1], l2W_p, l2b, emb_p + (size_t)((c - 3) & (NCH - 1)) * MCH * 128,
            dout + 16384, CH);
    }
}

// Round 10
// 1898.569 us; speedup vs baseline: 1.9915x; 1.9915x over previous
//
#include <hip/hip_runtime.h>
#include <cstddef>

typedef unsigned short u16;
typedef __bf16 bf16x8 __attribute__((ext_vector_type(8)));
typedef float f32x4 __attribute__((ext_vector_type(4)));
typedef unsigned short us4 __attribute__((ext_vector_type(4)));

__device__ __forceinline__ u16 f2b(float f) {
    unsigned u = __float_as_uint(f);
    u += 0x7fffu + ((u >> 16) & 1u);          // round-to-nearest-even
    return (u16)(u >> 16);
}
__device__ __forceinline__ float b2f(u16 h) { return __uint_as_float(((unsigned)h) << 16); }

__device__ __forceinline__ f32x4 mfma16(bf16x8 a, bf16x8 b, f32x4 c) {
    return __builtin_amdgcn_mfma_f32_16x16x32_bf16(a, b, c, 0, 0, 0);
}

// barrier WITHOUT vmcnt drain: global stores/prefetch loads stay in flight.
__device__ __forceinline__ void bar_lds() {
    asm volatile("s_waitcnt lgkmcnt(0)\n\ts_barrier" ::: "memory");
}

// B=256, S=512, D=128, H=256, HH=128, L=64.  chunk = 32 steps, 16 chunks.
#define CH   32
#define NCH  16
#define MCH  (CH * 256)   // rows per chunk = 8192

// ---------------------------------------------------------------------------
// pack: W [N][K] f32 -> MFMA B-fragments bf16; frag f=(nt*KT+kt): 64 lanes x 8
//   B[k][n] = W[n][k],  n = nt*16 + (lane&15),  k = kt*32 + (lane>>4)*8 + j
// ---------------------------------------------------------------------------
struct PackSeg { const float* src; u16* dst; int K; int nfrag; };
struct PackArgs { PackSeg seg[8]; };

__global__ __launch_bounds__(64) void pack_all(PackArgs pa) {
    int f = blockIdx.x;
    int i = 0;
    while (i < 7 && f >= pa.seg[i].nfrag) { f -= pa.seg[i].nfrag; i++; }
    const float* W = pa.seg[i].src;
    u16* out = pa.seg[i].dst;
    int K = pa.seg[i].K;
    int lane = threadIdx.x, q = lane >> 4, ln = lane & 15;
    int KT = K >> 5;
    int nt = f / KT, kt = f % KT;
    int n = nt * 16 + ln;
    int kb = kt * 32 + q * 8;
#pragma unroll
    for (int j = 0; j < 8; j++)
        out[((size_t)f * 64 + lane) * 8 + j] = f2b(W[(size_t)n * K + kb + j]);
}

// ---------------------------------------------------------------------------
__global__ void zero_kernel(float* __restrict__ st, float* __restrict__ lossslot) {
    int i = blockIdx.x * 256 + threadIdx.x;
    if (i < 196608) st[i] = 0.f;
    if (i == 0) *lossslot = 0.f;
}

// emb[row=t*256+b][d] = path[tok0][d] + sys[tok1][d]   (bf16). 16 rows/block.
__global__ __launch_bounds__(256) void embed_kernel(const int* __restrict__ tok,
                                                    const float* __restrict__ pw,
                                                    const float* __restrict__ sw,
                                                    u16* __restrict__ emb) {
    int col = threadIdx.x & 127;
    int half = threadIdx.x >> 7;
    int rbase = blockIdx.x * 16;
#pragma unroll
    for (int i = 0; i < 8; i++) {
        int r = rbase + i * 2 + half;   // row = t*256 + b
        int b = r & 255, t = r >> 8;
        const int* tp = tok + ((size_t)b * 512 + t) * 2;
        float v = pw[(size_t)tp[0] * 128 + col] + sw[(size_t)tp[1] * 128 + col];
        emb[(size_t)r * 128 + col] = f2b(v);
    }
}

// ---------------------------------------------------------------------------
// gemm body (512 thr): gi[M=8192][N] = X @ W.T + bias (+bhh for r,z gates),
// written TRANSPOSED: giT[(t*16+bg)*N + g][16] with bl=batch%16 innermost,
// so rec's per-step C-init is contiguous b64 loads.
// ---------------------------------------------------------------------------
template <int K, int N>
__device__ __forceinline__ void gemm_body(int bid, char* ldsraw,
                                          const u16* __restrict__ X,
                                          const u16* __restrict__ Wp,
                                          const float* __restrict__ bias,
                                          const float* __restrict__ bhh,
                                          u16* __restrict__ out) {
    constexpr int NH = N / 2, KT = K / 32, NTL = NH / 16;
    u16* wl = (u16*)ldsraw;
    int tid = threadIdx.x, wid = tid >> 6, lane = tid & 63, q = lane >> 4, ln = lane & 15;
    int half = bid & 1, mg = bid >> 1;
    {
        const bf16x8* src = (const bf16x8*)(Wp + (size_t)half * NH * K);
        bf16x8* dst = (bf16x8*)wl;
#pragma unroll
        for (int i = 0; i < NH * K / 8 / 512; i++) dst[tid + i * 512] = src[tid + i * 512];
    }
    __syncthreads();
    int m0 = (mg * 8 + wid) * 16;
    int t = m0 >> 8, bg = (m0 >> 4) & 15;
    u16* obase = out + (size_t)(t * 16 + bg) * N * 16;
    bf16x8 af[KT];
#pragma unroll
    for (int kt = 0; kt < KT; kt++)
        af[kt] = *(const bf16x8*)(X + (size_t)(m0 + ln) * K + kt * 32 + q * 8);
    for (int nt = 0; nt < NTL; nt++) {
        f32x4 acc = {0.f, 0.f, 0.f, 0.f};
#pragma unroll
        for (int kt = 0; kt < KT; kt++)
            acc = mfma16(af[kt], *(const bf16x8*)&wl[((nt * KT + kt) * 64 + lane) * 8], acc);
        int g = half * NH + nt * 16 + ln;
        float bv = bias[g] + ((g < 2 * (N / 3)) ? bhh[g] : 0.f);
        us4 v;
#pragma unroll
        for (int r = 0; r < 4; r++) v[r] = f2b(acc[r] + bv);
        *(us4*)&obase[(size_t)g * 16 + 4 * q] = v;
    }
}

template <int K, int N>
__global__ __launch_bounds__(512, 2) void gemm_kernel(const u16* __restrict__ X,
                                                      const u16* __restrict__ Wp,
                                                      const float* __restrict__ bias,
                                                      const float* __restrict__ bhh,
                                                      u16* __restrict__ out) {
    __shared__ char lds[98304];
    gemm_body<K, N>(blockIdx.x, lds, X, Wp, bias, bhh, out);
}

// ---------------------------------------------------------------------------
// loss body (512 thr, 64 blocks): recon = h2 @ l2W.T + l2b ; MSE vs emb chunk
// ---------------------------------------------------------------------------
__device__ __forceinline__ void loss_body(int bid, char* ldsraw,
                                          const u16* __restrict__ h2d,
                                          const u16* __restrict__ Wp,
                                          const float* __restrict__ l2b,
                                          const u16* __restrict__ embc,
                                          float* __restrict__ loss) {
    float* red = (float*)ldsraw;
    int tid = threadIdx.x, wid = tid >> 6, lane = tid & 63, q = lane >> 4, ln = lane & 15;
    int m0 = (bid * 8 + wid) * 16;
    bf16x8 af[8];
#pragma unroll
    for (int kt = 0; kt < 8; kt++)
        af[kt] = *(const bf16x8*)(h2d + (size_t)(m0 + ln) * 256 + kt * 32 + q * 8);
    float ls = 0.f;
#pragma unroll
    for (int nt = 0; nt < 8; nt++) {
        f32x4 acc = {0.f, 0.f, 0.f, 0.f};
#pragma unroll
        for (int kt = 0; kt < 8; kt++)
            acc = mfma16(af[kt], *(const bf16x8*)(Wp + ((size_t)(nt * 8 + kt) * 64 + lane) * 8), acc);
        int g = nt * 16 + ln;
        float bv = l2b[g];
#pragma unroll
        for (int r = 0; r < 4; r++) {
            float rec = acc[r] + bv;
            float ev = b2f(embc[(size_t)(m0 + q * 4 + r) * 128 + g]);
            float d = rec - ev;
            ls += d * d;
        }
    }
    red[tid] = ls;
    __syncthreads();
    for (int s = 256; s > 0; s >>= 1) {
        if (tid < s) red[tid] += red[tid + s];
        __syncthreads();
    }
    if (tid == 0) atomicAdd(loss, red[0] * (1.f / 16777216.f));
}

// ---------------------------------------------------------------------------
// Recurrent GRU body -- EXACT R8 structure (proven best operating point):
// 16 batches/WG, 8 waves, 2 waves/SIMD. Register-wall arithmetic: 48 weight
// frags/wave = 192 regs (invariant under tile-split direction) + ~100 working
// set vs 256/wave cap -> ~1.5 tiles MUST live outside registers. Config:
// compiler keeps ~4 tiles in AGPRs + juggles, 1 explicit LDS tile (WLDS),
// kh-outer 6-chain interleave for ILP. Pin attempts (R9 "+a"), all-reg (R7),
// 1-wave/SIMD (R5), hh-outer (R6) all regressed -- do not revisit.
// bhn folded into n-gate C-init; h double-buffered in LDS, ONE light
// barrier/step; gi prefetched one step ahead from the transposed layout.
// ---------------------------------------------------------------------------
template <int H, bool GI_CONST, bool WRITE_SEQ>
__device__ __forceinline__ void rec_body(int bid, char* ldsraw,
                                         const u16* __restrict__ giT,
                                         const float* __restrict__ gic,
                                         const u16* __restrict__ Wp,
                                         const float* __restrict__ bhh,
                                         float* __restrict__ hstate,
                                         u16* __restrict__ hseq, int steps) {
    constexpr int G3 = 3 * H;
    constexpr int KT = H / 32;
    constexpr int NHF = H / 128;            // h-slices per wave: 2 (H=256) / 1 (H=128)
    constexpr int HP = H + 8;
    constexpr bool WLDS = (H == 256);       // tile (g=2,hh=NHF-1) lives in LDS
    u16* wl = (u16*)ldsraw;                 // 8 waves x KT frags x 64 x 8 u16
    u16 (*hl)[16][HP] = (u16 (*)[16][HP])(ldsraw + (WLDS ? 65536 : 0));

    const int tid = threadIdx.x, w = tid >> 6, lane = tid & 63, q = lane >> 4, ln = lane & 15;
    const int b0 = bid * 16;
    const bf16x8* wpv = (const bf16x8*)Wp;

    // ---- resident weights (the (g=2,hh=NHF-1) slot stays in LDS if WLDS) ----
    bf16x8 wfr[3][NHF][KT];
#pragma unroll
    for (int g = 0; g < 3; g++)
#pragma unroll
        for (int hh = 0; hh < NHF; hh++) {
            if (WLDS && g == 2 && hh == NHF - 1) continue;
#pragma unroll
            for (int kt = 0; kt < KT; kt++)
                wfr[g][hh][kt] = wpv[((size_t)(g * (H / 16) + NHF * w + hh) * KT + kt) * 64 + lane];
        }
    if (WLDS) {
#pragma unroll
        for (int kt = 0; kt < KT; kt++)
            *(bf16x8*)&wl[((w * KT + kt) * 64 + lane) * 8] =
                wpv[((size_t)(2 * (H / 16) + NHF * w + (NHF - 1)) * KT + kt) * 64 + lane];
    }
    float bhn_r[NHF];
#pragma unroll
    for (int hh = 0; hh < NHF; hh++) bhn_r[hh] = bhh[2 * H + 16 * (NHF * w + hh) + ln];

    // ---- init h (bf16-rounded, matches chunk carry) ----
    float hold[NHF][4];
#pragma unroll
    for (int hh = 0; hh < NHF; hh++)
#pragma unroll
        for (int rg = 0; rg < 4; rg++) {
            const int b = 4 * q + rg, k = 16 * (NHF * w + hh) + ln;
            u16 hb = f2b(hstate[(size_t)(b0 + b) * H + k]);
            hold[hh][rg] = b2f(hb);
            hl[0][b][k] = hb;
        }

    // ---- gi: constant (f32) or transposed-chunk prefetch (us4/lane/tile) ----
    float gcf[3][NHF][4];
    us4 gp[3][NHF];
    if (GI_CONST) {
#pragma unroll
        for (int g = 0; g < 3; g++)
#pragma unroll
            for (int hh = 0; hh < NHF; hh++)
#pragma unroll
                for (int rg = 0; rg < 4; rg++)
                    gcf[g][hh][rg] =
                        gic[(size_t)(b0 + 4 * q + rg) * G3 + g * H + 16 * (NHF * w + hh) + ln];
    } else {
        const u16* blk = giT + (size_t)bid * G3 * 16;
#pragma unroll
        for (int g = 0; g < 3; g++)
#pragma unroll
            for (int hh = 0; hh < NHF; hh++)
                gp[g][hh] = *(const us4*)&blk[(g * H + 16 * (NHF * w + hh) + ln) * 16 + 4 * q];
    }
    bar_lds();

    for (int t = 0; t < steps; t++) {
        const int p = t & 1;
        // ---- C-init: r,z from gi; n-gate from bhn (folded); n-gi kept aside ----
        float gf2[NHF][4];
        f32x4 acc[3][NHF];
#pragma unroll
        for (int hh = 0; hh < NHF; hh++) {
#pragma unroll
            for (int rg = 0; rg < 4; rg++) {
                if (GI_CONST) {
                    acc[0][hh][rg] = gcf[0][hh][rg];
                    acc[1][hh][rg] = gcf[1][hh][rg];
                    gf2[hh][rg] = gcf[2][hh][rg];
                } else {
                    acc[0][hh][rg] = b2f(gp[0][hh][rg]);
                    acc[1][hh][rg] = b2f(gp[1][hh][rg]);
                    gf2[hh][rg] = b2f(gp[2][hh][rg]);
                }
                acc[2][hh][rg] = bhn_r[hh];
            }
        }
        // prefetch next step's gi (single-buffered; consumed above)
        if (!GI_CONST) {
            const int tn = (t + 1 < steps) ? t + 1 : t;
            const u16* blk = giT + (size_t)(tn * 16 + bid) * G3 * 16;
#pragma unroll
            for (int g = 0; g < 3; g++)
#pragma unroll
                for (int hh = 0; hh < NHF; hh++)
                    gp[g][hh] = *(const us4*)&blk[(g * H + 16 * (NHF * w + hh) + ln) * 16 + 4 * q];
        }

        // ---- gh = h @ Whh.T : kh-outer, 6 chains interleaved (max ILP) ----
#pragma unroll
        for (int kh = 0; kh < KT / 2; kh++) {
            bf16x8 a0 = *(const bf16x8*)&hl[p][ln][(2 * kh) * 32 + q * 8];
            bf16x8 a1 = *(const bf16x8*)&hl[p][ln][(2 * kh + 1) * 32 + q * 8];
#pragma unroll
            for (int g = 0; g < 3; g++)
#pragma unroll
                for (int hh = 0; hh < NHF; hh++) {
                    if (WLDS && g == 2 && hh == NHF - 1) {
                        bf16x8 w0 = *(const bf16x8*)&wl[((w * KT + 2 * kh) * 64 + lane) * 8];
                        bf16x8 w1 = *(const bf16x8*)&wl[((w * KT + 2 * kh + 1) * 64 + lane) * 8];
                        acc[g][hh] = mfma16(a0, w0, acc[g][hh]);
                        acc[g][hh] = mfma16(a1, w1, acc[g][hh]);
                    } else {
                        acc[g][hh] = mfma16(a0, wfr[g][hh][2 * kh], acc[g][hh]);
                        acc[g][hh] = mfma16(a1, wfr[g][hh][2 * kh + 1], acc[g][hh]);
                    }
                }
        }

        u16* hsb = WRITE_SEQ ? (hseq + ((size_t)t * 256 + b0) * H) : nullptr;
        // ---- in-register recombine ----
#pragma unroll
        for (int hh = 0; hh < NHF; hh++) {
            const int k = 16 * (NHF * w + hh) + ln;
#pragma unroll
            for (int rg = 0; rg < 4; rg++) {
                float xr = acc[0][hh][rg];
                float xz = acc[1][hh][rg];
                float hn = acc[2][hh][rg];          // bhn already in C-init
                float r = __builtin_amdgcn_rcpf(1.f + __builtin_amdgcn_exp2f(-1.44269504f * xr));
                float z = __builtin_amdgcn_rcpf(1.f + __builtin_amdgcn_exp2f(-1.44269504f * xz));
                float y = gf2[hh][rg] + r * hn;
                float e2 = __builtin_amdgcn_exp2f(2.88539008f * y);
                float n = 1.f - 2.f * __builtin_amdgcn_rcpf(e2 + 1.f);
                float hv = n + z * (hold[hh][rg] - n);
                u16 hb = f2b(hv);
                hold[hh][rg] = b2f(hb);
                hl[p ^ 1][4 * q + rg][k] = hb;
                if (WRITE_SEQ) hsb[(size_t)(4 * q + rg) * H + k] = hb;
            }
        }
        bar_lds();
    }
#pragma unroll
    for (int hh = 0; hh < NHF; hh++)
#pragma unroll
        for (int rg = 0; rg < 4; rg++)
            hstate[(size_t)(b0 + 4 * q + rg) * H + 16 * (NHF * w + hh) + ln] = hold[hh][rg];
}

// ---------------------------------------------------------------------------
// pair dispatches: independent WGs. rec WGs lowest blockIdx grab CUs first;
// 98 KB LDS pins 1 WG/CU everywhere (gemm WGs never share a rec CU).
// ---------------------------------------------------------------------------
__global__ __launch_bounds__(512, 2) void enc_pair(
    int nb1, int nb2, int ng1,
    const u16* r1gi, const u16* r1W, const float* r1bhh, float* r1st, u16* r1seq,
    const u16* r2gi, const u16* r2W, const float* r2bhh, float* r2st,
    const u16* g1X, const u16* g1W, const float* g1b, const float* g1bhh, u16* g1out,
    const u16* g2X, const u16* g2W, const float* g2b, const float* g2bhh, u16* g2out,
    int steps) {
    __shared__ char lds[98304];
    int b = blockIdx.x;
    if (b < nb1)
        rec_body<256, false, true>(b, lds, r1gi, nullptr, r1W, r1bhh, r1st, r1seq, steps);
    else if (b < nb1 + nb2)
        rec_body<128, false, false>(b - nb1, lds, r2gi, nullptr, r2W, r2bhh, r2st, nullptr, steps);
    else if (b < nb1 + nb2 + ng1)
        gemm_body<128, 768>(b - nb1 - nb2, lds, g1X, g1W, g1b, g1bhh, g1out);
    else
        gemm_body<256, 384>(b - nb1 - nb2 - ng1, lds, g2X, g2W, g2b, g2bhh, g2out);
}

__global__ __launch_bounds__(512, 2) void dec_pair(
    int nb1, int nb2, int ng,
    const float* r1gic, const u16* r1W, const float* r1bhh, float* r1st, u16* r1seq,
    const u16* r2gi, const u16* r2W, const float* r2bhh, float* r2st, u16* r2seq,
    const u16* gX, const u16* gW, const float* gb, const float* gbhh, u16* gout,
    const u16* lh2, const u16* lW, const float* l2b, const u16* lemb, float* lloss,
    int steps) {
    __shared__ char lds[98304];
    int b = blockIdx.x;
    if (b < nb1)
        rec_body<128, true, true>(b, lds, nullptr, r1gic, r1W, r1bhh, r1st, r1seq, steps);
    else if (b < nb1 + nb2)
        rec_body<256, false, true>(b - nb1, lds, r2gi, nullptr, r2W, r2bhh, r2st, r2seq, steps);
    else if (b < nb1 + nb2 + ng)
        gemm_body<128, 768>(b - nb1 - nb2, lds, gX, gW, gb, gbhh, gout);
    else
        loss_body(b - nb1 - nb2 - ng, lds, lh2, lW, l2b, lemb, lloss);
}

// ---------------------------------------------------------------------------
// latent = st2 @ l1_W.T + l1_b (-> d_out) ; gi1dec = latent @ d1_Wih.T + d1bih
// (+ d1bhh folded for r,z gates)
// ---------------------------------------------------------------------------
__global__ __launch_bounds__(128) void latent_kernel(const float* __restrict__ st2,
                                                     const float* __restrict__ l1W,
                                                     const float* __restrict__ l1b,
                                                     const float* __restrict__ d1Wih,
                                                     const float* __restrict__ d1bih,
                                                     const float* __restrict__ d1bhh,
                                                     float* __restrict__ dout,
                                                     float* __restrict__ gi1dec) {
    __shared__ float hv[128], lat[64];
    int b = blockIdx.x, tid = threadIdx.x;
    hv[tid] = st2[(size_t)b * 128 + tid];
    __syncthreads();
    if (tid < 64) {
        float s = l1b[tid];
        for (int k = 0; k < 128; k++) s += l1W[tid * 128 + k] * hv[k];
        dout[b * 64 + tid] = s;
        lat[tid] = s;
    }
    __syncthreads();
    for (int g = tid; g < 384; g += 128) {
        float s = d1bih[g] + (g < 256 ? d1bhh[g] : 0.f);
        for (int k = 0; k < 64; k++) s += d1Wih[g * 64 + k] * lat[k];
        gi1dec[(size_t)b * 384 + g] = s;
    }
}

// ---------------------------------------------------------------------------
extern "C" void kernel_launch(void* const* d_in, const int* in_sizes, int n_in,
                              void* d_out, int out_size, void* d_ws, size_t ws_size,
                              hipStream_t stream) {
    (void)in_sizes; (void)n_in; (void)out_size; (void)ws_size;
    const int*   tok   = (const int*)d_in[0];
    const float* pw    = (const float*)d_in[1];
    const float* sw    = (const float*)d_in[2];
    const float* e1Wih = (const float*)d_in[3];
    const float* e1Whh = (const float*)d_in[4];
    const float* e1bih = (const float*)d_in[5];
    const float* e1bhh = (const float*)d_in[6];
    const float* e2Wih = (const float*)d_in[7];
    const float* e2Whh = (const float*)d_in[8];
    const float* e2bih = (const float*)d_in[9];
    const float* e2bhh = (const float*)d_in[10];
    const float* l1W   = (const float*)d_in[11];
    const float* l1b   = (const float*)d_in[12];
    const float* d1Wih = (const float*)d_in[13];
    const float* d1Whh = (const float*)d_in[14];
    const float* d1bih = (const float*)d_in[15];
    const float* d1bhh = (const float*)d_in[16];
    const float* d2Wih = (const float*)d_in[17];
    const float* d2Whh = (const float*)d_in[18];
    const float* d2bih = (const float*)d_in[19];
    const float* d2bhh = (const float*)d_in[20];
    const float* l2W   = (const float*)d_in[21];
    const float* l2b   = (const float*)d_in[22];
    float* dout = (float*)d_out;

    char* base = (char*)d_ws;
    size_t o = 0;
    auto alloc = [&](size_t bytes) { size_t r = o; o += (bytes + 255) & ~(size_t)255; return r; };
    u16* e1Wih_p = (u16*)(base + alloc(196608));
    u16* e1Whh_p = (u16*)(base + alloc(393216));
    u16* e2Wih_p = (u16*)(base + alloc(196608));
    u16* e2Whh_p = (u16*)(base + alloc(98304));
    u16* d1Whh_p = (u16*)(base + alloc(98304));
    u16* d2Wih_p = (u16*)(base + alloc(196608));
    u16* d2Whh_p = (u16*)(base + alloc(393216));
    u16* l2W_p   = (u16*)(base + alloc(65536));
    u16* emb_p   = (u16*)(base + alloc((size_t)131072 * 128 * 2));
    u16* giA0    = (u16*)(base + alloc((size_t)MCH * 768 * 2));   // transposed
    u16* giA1    = (u16*)(base + alloc((size_t)MCH * 768 * 2));
    u16* giB0    = (u16*)(base + alloc((size_t)MCH * 384 * 2));   // transposed
    u16* giB1    = (u16*)(base + alloc((size_t)MCH * 384 * 2));
    u16* h1c0    = (u16*)(base + alloc((size_t)MCH * 256 * 2));   // row layout
    u16* h1c1    = (u16*)(base + alloc((size_t)MCH * 256 * 2));
    u16* h2c0    = (u16*)(base + alloc((size_t)MCH * 256 * 2));
    u16* h2c1    = (u16*)(base + alloc((size_t)MCH * 256 * 2));
    float* st1 = (float*)(base + alloc(256 * 256 * 4));
    float* st2 = (float*)(base + alloc(256 * 128 * 4));
    float* st3 = (float*)(base + alloc(256 * 128 * 4));
    float* st4 = (float*)(base + alloc(256 * 256 * 4));
    float* gi1dec = (float*)(base + alloc(256 * 384 * 4));
    u16* giA[2] = {giA0, giA1};
    u16* giB[2] = {giB0, giB1};
    u16* h1c[2] = {h1c0, h1c1};
    u16* h2c[2] = {h2c0, h2c1};

    PackArgs pa;
    pa.seg[0] = {e1Wih, e1Wih_p, 128, 192};
    pa.seg[1] = {e1Whh, e1Whh_p, 256, 384};
    pa.seg[2] = {e2Wih, e2Wih_p, 256, 192};
    pa.seg[3] = {e2Whh, e2Whh_p, 128, 96};
    pa.seg[4] = {d1Whh, d1Whh_p, 128, 96};
    pa.seg[5] = {d2Wih, d2Wih_p, 128, 192};
    pa.seg[6] = {d2Whh, d2Whh_p, 256, 384};
    pa.seg[7] = {l2W,   l2W_p,   256, 64};
    pack_all<<<1600, 64, 0, stream>>>(pa);
    zero_kernel<<<769, 256, 0, stream>>>(st1, dout + 16384);  // st1..st4 contiguous
    embed_kernel<<<8192, 256, 0, stream>>>(tok, pw, sw, emb_p);

    // ---------------- encoder: e1rec(c) || e2rec(c-2) || e1gemm(c+1) || e2gemm(c-1)
    gemm_kernel<128, 768><<<128, 512, 0, stream>>>(emb_p, e1Wih_p, e1bih, e1bhh, giA[0]);
    for (int c = 0; c < NCH; c++) {
        int nb2 = (c >= 2) ? 16 : 0;
        int ng1 = (c <= NCH - 2) ? 128 : 0;
        int ng2 = (c >= 1) ? 128 : 0;
        enc_pair<<<16 + nb2 + ng1 + ng2, 512, 0, stream>>>(16, nb2, ng1,
            giA[c & 1], e1Whh_p, e1bhh, st1, h1c[c & 1],
            giB[(c - 2) & 1], e2Whh_p, e2bhh, st2,
            emb_p + (size_t)((c + 1) & (NCH - 1)) * MCH * 128, e1Wih_p, e1bih, e1bhh,
            giA[(c + 1) & 1],
            h1c[(c - 1) & 1], e2Wih_p, e2bih, e2bhh, giB[(c - 1) & 1], CH);
    }
    // tails: e2rec(NCH-2) || e2gemm(NCH-1);  e2rec(NCH-1)
    enc_pair<<<16 + 128, 512, 0, stream>>>(0, 16, 0,
        giA[0], e1Whh_p, e1bhh, st1, h1c[0],
        giB[(NCH - 2) & 1], e2Whh_p, e2bhh, st2,
        emb_p, e1Wih_p, e1bih, e1bhh, giA[0],
        h1c[(NCH - 1) & 1], e2Wih_p, e2bih, e2bhh, giB[(NCH - 1) & 1], CH);
    enc_pair<<<16, 512, 0, stream>>>(0, 16, 0,
        giA[0], e1Whh_p, e1bhh, st1, h1c[0],
        giB[(NCH - 1) & 1], e2Whh_p, e2bhh, st2,
        emb_p, e1Wih_p, e1bih, e1bhh, giA[0],
        h1c[0], e2Wih_p, e2bih, e2bhh, giB[0], CH);

    latent_kernel<<<256, 128, 0, stream>>>(st2, l1W, l1b, d1Wih, d1bih, d1bhh, dout, gi1dec);

    // ---------------- decoder: d1rec(c) || d2gemm(c-1) || d2rec(c-2) || loss(c-3)
    for (int c = 0; c <= NCH + 2; c++) {
        int nb1 = (c <= NCH - 1) ? 16 : 0;
        int ng  = (c >= 1 && c <= NCH) ? 128 : 0;
        int nb2 = (c >= 2 && c <= NCH + 1) ? 16 : 0;
        int nl  = (c >= 3) ? 64 : 0;
        dec_pair<<<nb1 + nb2 + ng + nl, 512, 0, stream>>>(nb1, nb2, ng,
            gi1dec, d1Whh_p, d1bhh, st3, h1c[c & 1],
            giA[(c - 2) & 1], d2Whh_p, d2bhh, st4, h2c[(c - 2) & 1],
            h1c[(c - 1) & 1], d2Wih_p, d2bih, d2bhh, giA[(c - 1) & 1],
            h2c[(c - 3) & 1], l2W_p, l2b, emb_p + (size_t)((c - 3) & (NCH - 1)) * MCH * 128,
            dout + 16384, CH);
    }
}